// Round 2
// baseline (925.374 us; speedup 1.0000x reference)
//
#include <hip/hip_runtime.h>
#include <hip/hip_bf16.h>
#include <cstdint>

#define G_ 1024
#define B_ 256
#define H_ 128
#define NIN_ 64
#define P_ 523776   // G*(G-1)/2

typedef __bf16 bf16x8 __attribute__((ext_vector_type(8)));
typedef float f32x16 __attribute__((ext_vector_type(16)));

__device__ __forceinline__ float bf2f(unsigned short h) {
    unsigned int u = ((unsigned int)h) << 16;
    return __builtin_bit_cast(float, u);
}
__device__ __forceinline__ unsigned short f2bf(float f) {
    unsigned int u = __builtin_bit_cast(unsigned int, f);
    u += 0x7fffu + ((u >> 16) & 1u);   // round-to-nearest-even
    return (unsigned short)(u >> 16);
}

// -------- Kernel 0: detect input dtype. flag=1 -> bf16, flag=0 -> float32 ------
__global__ void k0_detect(const unsigned short* __restrict__ z, unsigned* __restrict__ flag) {
    int t = threadIdx.x;                       // 64 threads
    unsigned u = z[2 * t];                     // even ushorts
    unsigned e = (u >> 7) & 0xFFu;             // bf16 exponent field if bf16
    bool inr = (e >= 100u && e <= 140u);       // N(0,1) bf16 exponents live here
    unsigned long long m = __ballot(inr);
    if (t == 0) flag[0] = (__popcll(m) >= 40) ? 1u : 0u;
}

// ---------------- Kernel 1: c = z@Wc.T + bc ; E=exp(c), R=exp(-c); zero hpart ----
__global__ void k1_prep(const void* __restrict__ z,
                        const void* __restrict__ Wc,
                        const void* __restrict__ bc,
                        const unsigned* __restrict__ flag,
                        float* __restrict__ Ebuf, float* __restrict__ Rbuf,
                        float* __restrict__ hpart) {
    const bool isbf = (*flag != 0u);
    int idx = blockIdx.x * 256 + threadIdx.x;     // 0..262143 == B*G
    int b = idx >> 10, g = idx & 1023;
    float c;
    if (isbf) {
        const unsigned short* zr = (const unsigned short*)z + b * NIN_;
        const unsigned short* wr = (const unsigned short*)Wc + g * NIN_;
        c = bf2f(((const unsigned short*)bc)[g]);
        #pragma unroll
        for (int n = 0; n < NIN_; ++n) c += bf2f(zr[n]) * bf2f(wr[n]);
    } else {
        const float* zr = (const float*)z + b * NIN_;
        const float* wr = (const float*)Wc + g * NIN_;
        c = ((const float*)bc)[g];
        #pragma unroll
        for (int n = 0; n < NIN_; ++n) c += zr[n] * wr[n];
    }
    Ebuf[idx] = __expf(c);
    Rbuf[idx] = __expf(-c);
    hpart[idx] = 0.0f;                            // 8*256*128 == 262144 exactly
}

// ---------------- Kernel 2: fused sigma-produce + sigma-store + h GEMM ----------
// grid 512 (K-chunks of 1024 pairs), block 512 (8 waves: 4m x 2n)
__global__ void __launch_bounds__(512)
k2_main(const void* __restrict__ W1,
        const float* __restrict__ Ebuf, const float* __restrict__ Rbuf,
        const unsigned* __restrict__ flag,
        float* __restrict__ hpart,
        void* __restrict__ d_out) {
    __shared__ uint4 LA[2048];   // sigma tile: 8 pgroups x 256 rows, 16B frags (32 KB)
    __shared__ uint4 LB[1024];   // W1 tile: 8 pgroups x 128 rows (16 KB)

    const bool isbf = (*flag != 0u);
    const int t = threadIdx.x;
    const int wg = blockIdx.x;
    const int lane = t & 63;
    const int wave = t >> 6;
    const int m0 = (wave >> 1) * 64;
    const int n0 = (wave & 1) * 64;
    const int half = lane >> 5;
    const int r = lane & 31;

    unsigned short* sig_bf = (unsigned short*)d_out + 3 * 262144;
    float*          sig_f  = (float*)d_out + 3 * 262144;

    f32x16 acc00 = (f32x16)(0.0f), acc01 = (f32x16)(0.0f);
    f32x16 acc10 = (f32x16)(0.0f), acc11 = (f32x16)(0.0f);

    const int pg = t & 7;        // producer: p-group within BK tile
    const int brow = t >> 3;     // producer: row within 64-row pass

    const int chunk0 = wg * 1024;

    for (int kt = 0; kt < 16; ++kt) {
        const int kbase = chunk0 + kt * 64;
        __syncthreads();
        // ---- produce sigma tile -> LDS + global ----
        {
            const int p0 = kbase + pg * 8;
            if (p0 < P_) {
                // pair index -> (i0, j0): offset(i) = 1023*i - i*(i-1)/2
                float disc = (float)(4190209 - 8 * p0);
                int i0 = (int)((2047.0f - sqrtf(disc)) * 0.5f);
                while (1023 * (i0 + 1) - ((i0 + 1) * i0) / 2 <= p0) ++i0;
                while (1023 * i0 - (i0 * (i0 - 1)) / 2 > p0) --i0;
                int j0 = i0 + 1 + (p0 - (1023 * i0 - (i0 * (i0 - 1)) / 2));
                bool contig = (j0 + 7 <= 1023);
                #pragma unroll
                for (int pass = 0; pass < 4; ++pass) {
                    int b = pass * 64 + brow;
                    const float* Er = Ebuf + b * 1024;
                    const float* Rr = Rbuf + b * 1024;
                    float s[8];
                    if (contig) {
                        float rv = Rr[i0];
                        #pragma unroll
                        for (int m = 0; m < 8; ++m) s[m] = Er[j0 + m] * rv;
                    } else {
                        int ii = i0, jj = j0;
                        #pragma unroll
                        for (int m = 0; m < 8; ++m) {
                            s[m] = Er[jj] * Rr[ii];
                            if (++jj >= 1024) { ++ii; jj = ii + 1; }
                        }
                    }
                    uint4 pk;
                    pk.x = (unsigned)f2bf(s[0]) | ((unsigned)f2bf(s[1]) << 16);
                    pk.y = (unsigned)f2bf(s[2]) | ((unsigned)f2bf(s[3]) << 16);
                    pk.z = (unsigned)f2bf(s[4]) | ((unsigned)f2bf(s[5]) << 16);
                    pk.w = (unsigned)f2bf(s[6]) | ((unsigned)f2bf(s[7]) << 16);
                    LA[(pg * 256 + b) ^ pg] = pk;   // XOR swizzle kills 8-way write conflict
                    if (isbf) {
                        *(uint4*)(sig_bf + (size_t)b * P_ + p0) = pk;
                    } else {
                        float* dst = sig_f + (size_t)b * P_ + p0;
                        *(float4*)(dst)     = make_float4(s[0], s[1], s[2], s[3]);
                        *(float4*)(dst + 4) = make_float4(s[4], s[5], s[6], s[7]);
                    }
                }
            } else {
                uint4 zz = make_uint4(0, 0, 0, 0);
                #pragma unroll
                for (int pass = 0; pass < 4; ++pass)
                    LA[(pg * 256 + (pass * 64 + brow)) ^ pg] = zz;
            }
        }
        // ---- load W1 tile -> LDS (convert to bf16 if f32 input) ----
        #pragma unroll
        for (int s2 = 0; s2 < 2; ++s2) {
            int slot = t + s2 * 512;
            int n = slot >> 3;
            int pgb = slot & 7;
            int p = kbase + pgb * 8;
            uint4 w = make_uint4(0, 0, 0, 0);
            if (p < P_) {
                if (isbf) {
                    w = *(const uint4*)((const unsigned short*)W1 + (size_t)n * P_ + p);
                } else {
                    const float* wrow = (const float*)W1 + (size_t)n * P_ + p;
                    float4 f0 = *(const float4*)(wrow);
                    float4 f1 = *(const float4*)(wrow + 4);
                    w.x = (unsigned)f2bf(f0.x) | ((unsigned)f2bf(f0.y) << 16);
                    w.y = (unsigned)f2bf(f0.z) | ((unsigned)f2bf(f0.w) << 16);
                    w.z = (unsigned)f2bf(f1.x) | ((unsigned)f2bf(f1.y) << 16);
                    w.w = (unsigned)f2bf(f1.z) | ((unsigned)f2bf(f1.w) << 16);
                }
            }
            LB[(pgb * 128 + n) ^ pgb] = w;
        }
        __syncthreads();
        // ---- consume: 16 MFMA ----
        #pragma unroll
        for (int ks = 0; ks < 4; ++ks) {
            int kg = ks * 2 + half;
            bf16x8 a0 = __builtin_bit_cast(bf16x8, LA[(kg * 256 + (m0 + r)) ^ kg]);
            bf16x8 a1 = __builtin_bit_cast(bf16x8, LA[(kg * 256 + (m0 + 32 + r)) ^ kg]);
            bf16x8 b0 = __builtin_bit_cast(bf16x8, LB[(kg * 128 + (n0 + r)) ^ kg]);
            bf16x8 b1 = __builtin_bit_cast(bf16x8, LB[(kg * 128 + (n0 + 32 + r)) ^ kg]);
            acc00 = __builtin_amdgcn_mfma_f32_32x32x16_bf16(a0, b0, acc00, 0, 0, 0);
            acc01 = __builtin_amdgcn_mfma_f32_32x32x16_bf16(a0, b1, acc01, 0, 0, 0);
            acc10 = __builtin_amdgcn_mfma_f32_32x32x16_bf16(a1, b0, acc10, 0, 0, 0);
            acc11 = __builtin_amdgcn_mfma_f32_32x32x16_bf16(a1, b1, acc11, 0, 0, 0);
        }
    }
    // ---- epilogue: accumulate into one of 8 partial buffers ----
    float* hp = hpart + (wg & 7) * (B_ * H_);
    #pragma unroll
    for (int reg = 0; reg < 16; ++reg) {
        int row = (reg & 3) + 8 * (reg >> 2) + 4 * half;   // verified C/D layout
        atomicAdd(&hp[(m0 + row) * H_ + (n0 + r)],          acc00[reg]);
        atomicAdd(&hp[(m0 + row) * H_ + (n0 + 32 + r)],     acc01[reg]);
        atomicAdd(&hp[(m0 + 32 + row) * H_ + (n0 + r)],     acc10[reg]);
        atomicAdd(&hp[(m0 + 32 + row) * H_ + (n0 + 32 + r)],acc11[reg]);
    }
}

// ---------------- Kernel 3: sum partials + b1, BatchNorm(train) + ReLU ----------
__global__ void k3_bn(const float* __restrict__ hpart,
                      const void* __restrict__ b1,
                      const void* __restrict__ gamma,
                      const void* __restrict__ beta,
                      const unsigned* __restrict__ flag,
                      float* __restrict__ hpost) {
    const bool isbf = (*flag != 0u);
    int k = blockIdx.x;    // 0..127
    int b = threadIdx.x;   // 0..255
    float vb1, vg, vbeta;
    if (isbf) {
        vb1   = bf2f(((const unsigned short*)b1)[k]);
        vg    = bf2f(((const unsigned short*)gamma)[k]);
        vbeta = bf2f(((const unsigned short*)beta)[k]);
    } else {
        vb1   = ((const float*)b1)[k];
        vg    = ((const float*)gamma)[k];
        vbeta = ((const float*)beta)[k];
    }
    float h = vb1;
    #pragma unroll
    for (int q = 0; q < 8; ++q) h += hpart[q * (B_ * H_) + b * H_ + k];
    float s1 = h, s2 = h * h;
    #pragma unroll
    for (int m = 32; m >= 1; m >>= 1) {
        s1 += __shfl_xor(s1, m, 64);
        s2 += __shfl_xor(s2, m, 64);
    }
    __shared__ float rs1[4], rs2[4];
    if ((b & 63) == 0) { rs1[b >> 6] = s1; rs2[b >> 6] = s2; }
    __syncthreads();
    float S1 = rs1[0] + rs1[1] + rs1[2] + rs1[3];
    float S2 = rs2[0] + rs2[1] + rs2[2] + rs2[3];
    float mean = S1 * (1.0f / 256.0f);
    float var = S2 * (1.0f / 256.0f) - mean * mean;   // biased, as torch BN
    float hn = vg * (h - mean) * rsqrtf(var + 1e-3f) + vbeta;
    hpost[b * H_ + k] = fmaxf(hn, 0.0f);
}

// ---------------- Kernel 4: three heads + softmax(scale) ------------------------
__device__ __forceinline__ float dot8bf(uint4 a, const float* hv) {
    return bf2f((unsigned short)(a.x & 0xffffu)) * hv[0]
         + bf2f((unsigned short)(a.x >> 16))     * hv[1]
         + bf2f((unsigned short)(a.y & 0xffffu)) * hv[2]
         + bf2f((unsigned short)(a.y >> 16))     * hv[3]
         + bf2f((unsigned short)(a.z & 0xffffu)) * hv[4]
         + bf2f((unsigned short)(a.z >> 16))     * hv[5]
         + bf2f((unsigned short)(a.w & 0xffffu)) * hv[6]
         + bf2f((unsigned short)(a.w >> 16))     * hv[7];
}

__global__ void k4_heads(const float* __restrict__ hpost,
                         const void* __restrict__ Wscale, const void* __restrict__ bscale,
                         const void* __restrict__ Wshape, const void* __restrict__ bshape,
                         const void* __restrict__ Wdrop,  const void* __restrict__ bdrop,
                         const unsigned* __restrict__ flag,
                         void* __restrict__ d_out) {
    const bool isbf = (*flag != 0u);
    int b = blockIdx.x, t = threadIdx.x;
    __shared__ float hrow[H_];
    __shared__ float slog[G_];
    __shared__ float red[4];
    if (t < H_) hrow[t] = hpost[b * H_ + t];
    __syncthreads();
    #pragma unroll
    for (int gi = 0; gi < 4; ++gi) {
        int g = gi * 256 + t;
        float dsc = 0.f, dsh = 0.f, ddr = 0.f;
        float bsc, bsh, bdr;
        if (isbf) {
            const uint4* wsc = (const uint4*)((const unsigned short*)Wscale + g * H_);
            const uint4* wsh = (const uint4*)((const unsigned short*)Wshape + g * H_);
            const uint4* wdr = (const uint4*)((const unsigned short*)Wdrop  + g * H_);
            #pragma unroll
            for (int c = 0; c < 16; ++c) {
                float hv[8];
                #pragma unroll
                for (int j = 0; j < 8; ++j) hv[j] = hrow[c * 8 + j];
                dsc += dot8bf(wsc[c], hv);
                dsh += dot8bf(wsh[c], hv);
                ddr += dot8bf(wdr[c], hv);
            }
            bsc = bf2f(((const unsigned short*)bscale)[g]);
            bsh = bf2f(((const unsigned short*)bshape)[g]);
            bdr = bf2f(((const unsigned short*)bdrop)[g]);
        } else {
            const float4* wsc = (const float4*)((const float*)Wscale + g * H_);
            const float4* wsh = (const float4*)((const float*)Wshape + g * H_);
            const float4* wdr = (const float4*)((const float*)Wdrop  + g * H_);
            #pragma unroll
            for (int c = 0; c < 32; ++c) {
                float4 a = wsc[c], s = wsh[c], d = wdr[c];
                float h0 = hrow[c*4], h1 = hrow[c*4+1], h2 = hrow[c*4+2], h3 = hrow[c*4+3];
                dsc += a.x*h0 + a.y*h1 + a.z*h2 + a.w*h3;
                dsh += s.x*h0 + s.y*h1 + s.z*h2 + s.w*h3;
                ddr += d.x*h0 + d.y*h1 + d.z*h2 + d.w*h3;
            }
            bsc = ((const float*)bscale)[g];
            bsh = ((const float*)bshape)[g];
            bdr = ((const float*)bdrop)[g];
        }
        float vsh = dsh + bsh;
        float vdr = ddr + bdr;
        if (isbf) {
            ((unsigned short*)d_out)[(size_t)0 * 262144 + b * G_ + g] = f2bf(vsh);
            ((unsigned short*)d_out)[(size_t)2 * 262144 + b * G_ + g] = f2bf(vdr);
        } else {
            ((float*)d_out)[(size_t)0 * 262144 + b * G_ + g] = vsh;
            ((float*)d_out)[(size_t)2 * 262144 + b * G_ + g] = vdr;
        }
        slog[g] = dsc + bsc;
    }
    __syncthreads();
    // softmax over slog[0..1023]
    float mx = -1e30f;
    #pragma unroll
    for (int gi = 0; gi < 4; ++gi) mx = fmaxf(mx, slog[gi * 256 + t]);
    #pragma unroll
    for (int m = 32; m >= 1; m >>= 1) mx = fmaxf(mx, __shfl_xor(mx, m, 64));
    if ((t & 63) == 0) red[t >> 6] = mx;
    __syncthreads();
    mx = fmaxf(fmaxf(red[0], red[1]), fmaxf(red[2], red[3]));
    __syncthreads();
    float sum = 0.f;
    #pragma unroll
    for (int gi = 0; gi < 4; ++gi) sum += __expf(slog[gi * 256 + t] - mx);
    #pragma unroll
    for (int m = 32; m >= 1; m >>= 1) sum += __shfl_xor(sum, m, 64);
    if ((t & 63) == 0) red[t >> 6] = sum;
    __syncthreads();
    float inv = 1.0f / (red[0] + red[1] + red[2] + red[3]);
    #pragma unroll
    for (int gi = 0; gi < 4; ++gi) {
        int g = gi * 256 + t;
        float v = __expf(slog[g] - mx) * inv;
        if (isbf) ((unsigned short*)d_out)[(size_t)1 * 262144 + b * G_ + g] = f2bf(v);
        else      ((float*)d_out)[(size_t)1 * 262144 + b * G_ + g] = v;
    }
}

extern "C" void kernel_launch(void* const* d_in, const int* in_sizes, int n_in,
                              void* d_out, int out_size, void* d_ws, size_t ws_size,
                              hipStream_t stream) {
    const void* z      = d_in[0];
    const void* Wc     = d_in[1];
    const void* bc     = d_in[2];
    const void* W1     = d_in[3];
    const void* b1     = d_in[4];
    const void* gamma  = d_in[5];
    const void* beta   = d_in[6];
    const void* Wscale = d_in[7];
    const void* bscale = d_in[8];
    const void* Wshape = d_in[9];
    const void* bshape = d_in[10];
    const void* Wdrop  = d_in[11];
    const void* bdrop  = d_in[12];

    float* ws    = (float*)d_ws;
    unsigned* flag = (unsigned*)ws;     // ws[0]
    float* Ebuf  = ws + 64;             // 262144 f32
    float* Rbuf  = ws + 64 + 262144;    // 262144 f32
    float* hpart = ws + 64 + 524288;    // 8 * 32768 f32 (zeroed by k1)
    float* hpost = ws + 64 + 786432;    // 32768 f32

    k0_detect<<<1, 64, 0, stream>>>((const unsigned short*)z, flag);
    k1_prep<<<1024, 256, 0, stream>>>(z, Wc, bc, flag, Ebuf, Rbuf, hpart);
    k2_main<<<512, 512, 0, stream>>>(W1, Ebuf, Rbuf, flag, hpart, d_out);
    k3_bn<<<128, 256, 0, stream>>>(hpart, b1, gamma, beta, flag, hpost);
    k4_heads<<<256, 256, 0, stream>>>(hpost, Wscale, bscale, Wshape, bshape, Wdrop, bdrop, flag, d_out);
}